// Round 12
// baseline (277.850 us; speedup 1.0000x reference)
//
#include <hip/hip_runtime.h>

// CenterLoss: loss = 0.5/B * (FF - 2*DOT + CC)
//   FF  = sum_i ||f_i||^2                      (fp32, exact, pass kA)
//   DOT = sum_c S_c . newc_c                   (S_c from bf16 images)
//   CC  = sum_c count_c * ||newc_c||^2
//   newc_c = count_c>0 ? 0.5*centers_c + 0.5*S_c/count_c : centers_c
//
// R12: ALL global traffic sequential (random sub-4KB granules run at
// ~6.3 TB/s * granule/4KB on this chip -- translation-rate wall, R4-R11).
//   kA: per-block (256 rows) LDS counting sort by bucket=class>>5; rows
//       converted to bf16 into a 128KB LDS buffer at locally-sorted
//       positions; buffer dumped SEQUENTIALLY; FF in fp32.
//       Lane l owns dims {l,l+64,l+128,l+192} (4 strided dword loads) so
//       every LDS access is 2-way-conflict-free.
//   kB: block (q,g) streams 32 source-blocks' bucket-q pieces (contiguous),
//       ds_add into a 32-class x 256-dim LDS table, stores table to its own
//       partial part[g] (no zeroing, no global atomics).
//   k_epi: sum 16 partials -> DOT/CC; last block emits loss.

#define DDIM 256
#define ROWS_PB 256
#define NGRP 16

__device__ __forceinline__ unsigned short f2bf(float x) {
    unsigned u = __float_as_uint(x);
    unsigned r = (u + 0x7FFFu + ((u >> 16) & 1u)) >> 16;   // RNE
    return (unsigned short)r;
}
__device__ __forceinline__ float bf2f(unsigned short b) {
    return __uint_as_float(((unsigned)b) << 16);
}

__global__ __launch_bounds__(64) void k0_zero(float* __restrict__ scal16) {
    if (threadIdx.x < 16) scal16[threadIdx.x] = 0.f;
}

// ---- Pass A: local bucket-sort + bf16 staging + sequential dump + FF ----
__global__ __launch_bounds__(512) void kA_sort(const float* __restrict__ feats,
                                               const int* __restrict__ labels,
                                               ushort4* __restrict__ pay,
                                               unsigned char* __restrict__ glab,
                                               int* __restrict__ mat,
                                               float* __restrict__ scalars) {
    __shared__ ushort4 payL[ROWS_PB * 64];       // 128 KB bf16 staging
    __shared__ int map[ROWS_PB];
    __shared__ unsigned char locL[ROWS_PB];
    __shared__ int h[32], cur[32], scan[33];
    __shared__ float redf[8];

    int b = blockIdx.x, t = threadIdx.x, wave = t >> 6, lane = t & 63;
    int gbase = b * ROWS_PB;

    if (t < 32) h[t] = 0;
    __syncthreads();
    int mylbl = 0;
    if (t < ROWS_PB) {
        mylbl = labels[gbase + t];
        atomicAdd(&h[mylbl >> 5], 1);
    }
    __syncthreads();
    if (t == 0) {
        int s = 0;
#pragma unroll
        for (int i = 0; i < 32; ++i) { scan[i] = s; s += h[i]; }
        scan[32] = s;
    }
    __syncthreads();
    if (t < 32) cur[t] = scan[t];
    if (t < 33) mat[b * 33 + t] = scan[t];
    __syncthreads();
    if (t < ROWS_PB) {
        int pos = atomicAdd(&cur[mylbl >> 5], 1);
        map[t] = pos;
        locL[pos] = (unsigned char)(mylbl & 31);
    }
    __syncthreads();

    // P1: wave w streams rows w*32..w*32+31, 8 rows in flight.
    float ff = 0.f;
    int r0 = wave * 32;
    for (int it = 0; it < 4; ++it) {
        int rb = r0 + it * 8;
        float v[8][4];
#pragma unroll
        for (int j = 0; j < 8; ++j) {
            const float* rp = feats + (size_t)(gbase + rb + j) * DDIM + lane;
            v[j][0] = rp[0];
            v[j][1] = rp[64];
            v[j][2] = rp[128];
            v[j][3] = rp[192];
        }
#pragma unroll
        for (int j = 0; j < 8; ++j) {
            ff += v[j][0]*v[j][0] + v[j][1]*v[j][1]
                + v[j][2]*v[j][2] + v[j][3]*v[j][3];
            ushort4 o;
            o.x = f2bf(v[j][0]); o.y = f2bf(v[j][1]);
            o.z = f2bf(v[j][2]); o.w = f2bf(v[j][3]);
            int srow = map[rb + j];              // wave-uniform LDS broadcast
            payL[srow * 64 + lane] = o;          // 2-way bank, free
        }
    }
    __syncthreads();

    // P2: sequential dump of staging buffer + labels.
    {
        ushort4* dst = pay + (size_t)gbase * 64;
        for (int idx = t; idx < ROWS_PB * 64; idx += 512) dst[idx] = payL[idx];
        if (t < ROWS_PB) glab[gbase + t] = locL[t];
    }

#pragma unroll
    for (int off = 32; off > 0; off >>= 1) ff += __shfl_xor(ff, off);
    if (lane == 0) redf[wave] = ff;
    __syncthreads();
    if (t == 0) {
        float a = 0.f;
#pragma unroll
        for (int w = 0; w < 8; ++w) a += redf[w];
        atomicAdd(&scalars[0], a);
    }
}

// ---- Pass B: per-(bucket q, group g) 32-class LDS reduce -> part[g] ----
__global__ __launch_bounds__(512) void kB_reduce(const ushort4* __restrict__ pay,
                                                 const unsigned char* __restrict__ glab,
                                                 const int* __restrict__ mat,
                                                 float* __restrict__ part,
                                                 int* __restrict__ counts_part,
                                                 int nA) {
    __shared__ float table[32 * DDIM];   // 32 KB
    __shared__ int m0L[32], m1L[32], ccnt[32];

    int bid = blockIdx.x;
    int q = bid >> 4, g = bid & (NGRP - 1);
    int t = threadIdx.x, wave = t >> 6, lane = t & 63;
    int srcpb = nA / NGRP;               // 32

    for (int idx = t; idx < 32 * DDIM; idx += 512) table[idx] = 0.f;
    if (t < 32) {
        ccnt[t] = 0;
        int b = g * srcpb + t;
        m0L[t] = mat[b * 33 + q];
        m1L[t] = mat[b * 33 + q + 1];
    }
    __syncthreads();

    // wave w handles local source blocks w*4 .. w*4+3
    for (int bb = wave * 4; bb < wave * 4 + 4; ++bb) {
        int m0 = m0L[bb], m1 = m1L[bb];
        int base = (g * srcpb + bb) * ROWS_PB;
        int r = m0;
        for (; r + 4 <= m1; r += 4) {
            ushort4 u[4];
            int loc[4];
#pragma unroll
            for (int j = 0; j < 4; ++j)
                u[j] = pay[(size_t)(base + r + j) * 64 + lane];
#pragma unroll
            for (int j = 0; j < 4; ++j)
                loc[j] = glab[base + r + j];
#pragma unroll
            for (int j = 0; j < 4; ++j) {
                float* tb = &table[loc[j] * DDIM + lane];
                atomicAdd(tb,       bf2f(u[j].x));
                atomicAdd(tb + 64,  bf2f(u[j].y));
                atomicAdd(tb + 128, bf2f(u[j].z));
                atomicAdd(tb + 192, bf2f(u[j].w));
                if (lane == 0) atomicAdd(&ccnt[loc[j]], 1);
            }
        }
        for (; r < m1; ++r) {
            ushort4 u = pay[(size_t)(base + r) * 64 + lane];
            int loc = glab[base + r];
            float* tb = &table[loc * DDIM + lane];
            atomicAdd(tb,       bf2f(u.x));
            atomicAdd(tb + 64,  bf2f(u.y));
            atomicAdd(tb + 128, bf2f(u.z));
            atomicAdd(tb + 192, bf2f(u.w));
            if (lane == 0) atomicAdd(&ccnt[loc], 1);
        }
    }
    __syncthreads();

    // Non-atomic flush: this (q,g) exclusively owns part[g][q*32 .. q*32+31].
    {
        const float4* t4 = (const float4*)table;
        float4* p4 = (float4*)&part[((size_t)g * 1024 + q * 32) * DDIM];
        for (int idx = t; idx < 32 * DDIM / 4; idx += 512) p4[idx] = t4[idx];
        if (t < 32) counts_part[g * 1024 + q * 32 + t] = ccnt[t];
    }
}

// ---- Epilogue: one 64-thread block per class ----
__global__ __launch_bounds__(64) void k_epi(const float* __restrict__ part,
                                            const int* __restrict__ counts_part,
                                            const float* __restrict__ centers,
                                            float* __restrict__ scalars,
                                            int* __restrict__ ticket,
                                            float* __restrict__ out,
                                            int C, float invB) {
    int c = blockIdx.x, lane = threadIdx.x;
    float4 s = make_float4(0.f, 0.f, 0.f, 0.f);
    int n = 0;
#pragma unroll
    for (int g = 0; g < NGRP; ++g) {
        float4 p = *(const float4*)&part[((size_t)g * 1024 + c) * DDIM + lane * 4];
        s.x += p.x; s.y += p.y; s.z += p.z; s.w += p.w;
        n += counts_part[g * 1024 + c];
    }
    float4 co = *(const float4*)&centers[c * DDIM + lane * 4];
    float inv = (n > 0) ? 0.5f / (float)n : 0.f;
    float4 nc;
    nc.x = 0.5f * co.x + s.x * inv;   // n==0: s==0 -> dotv=ccv=0 regardless
    nc.y = 0.5f * co.y + s.y * inv;
    nc.z = 0.5f * co.z + s.z * inv;
    nc.w = 0.5f * co.w + s.w * inv;
    float dotv = nc.x * s.x + nc.y * s.y + nc.z * s.z + nc.w * s.w;
    float ccv  = (nc.x*nc.x + nc.y*nc.y + nc.z*nc.z + nc.w*nc.w) * (float)n;

#pragma unroll
    for (int off = 32; off > 0; off >>= 1) {
        dotv += __shfl_down(dotv, off);
        ccv  += __shfl_down(ccv, off);
    }
    if (lane == 0) {
        atomicAdd(&scalars[1], dotv);
        atomicAdd(&scalars[2], ccv);
        __threadfence();
        int old = atomicAdd(ticket, 1);
        if (old == C - 1) {
            __threadfence();
            float A  = atomicAdd(&scalars[0], 0.f);
            float Bv = atomicAdd(&scalars[1], 0.f);
            float E  = atomicAdd(&scalars[2], 0.f);
            out[0] = 0.5f * invB * (A - 2.f * Bv + E);
        }
    }
}

extern "C" void kernel_launch(void* const* d_in, const int* in_sizes, int n_in,
                              void* d_out, int out_size, void* d_ws, size_t ws_size,
                              hipStream_t stream) {
    const float* feats   = (const float*)d_in[0];
    const float* centers = (const float*)d_in[1];
    const int*   labels  = (const int*)d_in[2];

    int B = in_sizes[2];              // 131072
    int Dv = in_sizes[0] / B;         // 256 (kernel assumes 256)
    int C = in_sizes[1] / Dv;         // 1000 (<=1024 assumed)
    (void)Dv; (void)n_in; (void)ws_size; (void)out_size;

    int nA = B / ROWS_PB;             // 512 source blocks (B % 256 == 0)

    // ws layout (int offsets):
    // scalars[16] | mat[nA*33] | counts_part[NGRP*1024] | glab[B bytes]
    // | part[NGRP*1024*DDIM f32, 16B aligned] | pay[B*64 ushort4]
    int* W = (int*)d_ws;
    float* scalars   = (float*)W;                       // 16
    int* ticket      = W + 12;                          // scalars slot 12
    int* mat         = W + 16;                          // nA*33
    int* counts_part = mat + nA * 33;                   // NGRP*1024
    unsigned char* glab = (unsigned char*)(counts_part + NGRP * 1024);  // B bytes
    int lab_ints = B / 4;
    int* after_lab = counts_part + NGRP * 1024 + lab_ints;
    // align part to 16B (int offset multiple of 4)
    size_t off = (size_t)(after_lab - W);
    off = (off + 3) & ~(size_t)3;
    float* part = (float*)(W + off);                    // NGRP*1024*DDIM
    ushort4* pay = (ushort4*)(part + (size_t)NGRP * 1024 * DDIM);  // B*64

    k0_zero<<<1, 64, 0, stream>>>(scalars);
    kA_sort<<<nA, 512, 0, stream>>>(feats, labels, pay, glab, mat, scalars);
    kB_reduce<<<32 * NGRP, 512, 0, stream>>>(pay, glab, mat, part,
                                             counts_part, nA);
    k_epi<<<C, 64, 0, stream>>>(part, counts_part, centers, scalars, ticket,
                                (float*)d_out, C, 1.0f / (float)B);
}